// Round 19
// baseline (60.429 us; speedup 1.0000x reference)
//
#include <hip/hip_runtime.h>

#define IN   128
#define HID  16
#define OUT  64
#define BK   64        // nodes per bucket (bucket = dst >> 6)
#define EPB  4096      // edges per partition block (B=196 blocks)
#define CAP  2048      // staging capacity per bucket (mean ~1024, 30-sigma safe)
#define PBN  64        // nodes per proj block (8 per thread)

__device__ __forceinline__ void f4add(float4& a, const float4 v) {
    a.x += v.x; a.y += v.y; a.z += v.z; a.w += v.w;
}

// ---- K1 (fused): blocks [0,B) = block-local partition (first => overlapped).
//      Blocks [B, B+nproj) = proj, 64 nodes/block, 8 nodes/thread: each
//      weight-row LDS read reused 8x (x-row reads are half-wave broadcast).
__global__ void __launch_bounds__(256)
k_proj_part(const float* __restrict__ x,
            const float* __restrict__ Ws,
            const float* __restrict__ Wn,
            const int* __restrict__ src,
            const int* __restrict__ dst,
            float* __restrict__ xs,
            float* __restrict__ xn,
            int* __restrict__ loffT,
            unsigned* __restrict__ bedge,
            int n, int e, int K, int B) {
    __shared__ __align__(16) float smem[4224 + 8192];  // lwT[32][132] + lx[64][128]
    int tid = threadIdx.x;   // 256
    if ((int)blockIdx.x < B) {
        // ---- partition block (R16/R17-proven body, byte-identical) ----
        int* ism = (int*)smem;
        int* lh  = ism;            // [1024] counts, later cursors
        int* lsc = ism + 1024;     // [K+1]
        int* sm  = ism + 2050;     // [256]
        int blk = blockIdx.x;
        for (int i = tid; i < K; i += 256) lh[i] = 0;
        __syncthreads();
        const int4* d4 = (const int4*)dst;
        #pragma unroll
        for (int it = 0; it < EPB / 1024; ++it) {
            int i4 = blk * (EPB / 4) + it * 256 + tid;
            int elem = i4 * 4;
            if (elem + 3 < e) {
                int4 v = d4[i4];
                atomicAdd(&lh[v.x >> 6], 1);
                atomicAdd(&lh[v.y >> 6], 1);
                atomicAdd(&lh[v.z >> 6], 1);
                atomicAdd(&lh[v.w >> 6], 1);
            } else {
                for (int jj = elem; jj < e && jj < elem + 4; ++jj)
                    atomicAdd(&lh[dst[jj] >> 6], 1);
            }
        }
        __syncthreads();
        int C = (K + 255) >> 8;
        int i0 = tid * C, i1 = min(i0 + C, K);
        int s = 0;
        for (int i = i0; i < i1; ++i) s += lh[i];
        sm[tid] = s;
        __syncthreads();
        for (int off = 1; off < 256; off <<= 1) {
            int u = (tid >= off) ? sm[tid - off] : 0;
            __syncthreads();
            sm[tid] += u;
            __syncthreads();
        }
        int run = sm[tid] - s;
        for (int i = i0; i < i1; ++i) {
            int vv = lh[i];
            lsc[i] = run;
            run += vv;
        }
        if (tid == 255) lsc[K] = sm[255];
        __syncthreads();
        for (int bb = tid; bb <= K; bb += 256)
            loffT[(size_t)bb * B + blk] = lsc[bb];
        for (int bb = tid; bb < K; bb += 256) lh[bb] = lsc[bb];  // cursors
        __syncthreads();
        unsigned base = (unsigned)blk * EPB;
        const int4* s4 = (const int4*)src;
        #pragma unroll
        for (int it = 0; it < EPB / 1024; ++it) {
            int i4 = blk * (EPB / 4) + it * 256 + tid;
            int elem = i4 * 4;
            if (elem + 3 < e) {
                int4 sv = s4[i4];
                int4 dv = d4[i4];
                int p0 = atomicAdd(&lh[dv.x >> 6], 1);
                int p1 = atomicAdd(&lh[dv.y >> 6], 1);
                int p2 = atomicAdd(&lh[dv.z >> 6], 1);
                int p3 = atomicAdd(&lh[dv.w >> 6], 1);
                bedge[base + p0] = ((unsigned)sv.x << 6) | (unsigned)(dv.x & 63);
                bedge[base + p1] = ((unsigned)sv.y << 6) | (unsigned)(dv.y & 63);
                bedge[base + p2] = ((unsigned)sv.z << 6) | (unsigned)(dv.z & 63);
                bedge[base + p3] = ((unsigned)sv.w << 6) | (unsigned)(dv.w & 63);
            } else {
                for (int jj = elem; jj < e && jj < elem + 4; ++jj) {
                    int pos = atomicAdd(&lh[dst[jj] >> 6], 1);
                    bedge[base + pos] = ((unsigned)src[jj] << 6) | (unsigned)(dst[jj] & 63);
                }
            }
        }
    } else {
        // ---- proj block: 64 nodes, 8 per thread (rows r0 + 8q, q=0..7) ----
        float (*lwT)[132] = (float (*)[132])smem;          // [32][132]
        float (*lx)[IN]   = (float (*)[IN])(smem + 4224);  // [64][128]
        for (int i = tid; i < IN * 32; i += 256) {
            int k = i >> 5, j = i & 31;
            lwT[j][k] = (j < HID) ? Ws[k * HID + j] : Wn[k * HID + (j - 16)];
        }
        int node0 = (blockIdx.x - B) * PBN;
        const float4* x4 = (const float4*)x;
        float4* lx4 = (float4*)lx;     // [64][32] float4 = 2048
        #pragma unroll
        for (int q = 0; q < 8; ++q) {
            int i = q * 256 + tid;
            int r = i >> 5, c4 = i & 31;
            int node = node0 + r;
            lx4[i] = (node < n) ? x4[(size_t)node * 32 + c4]
                                : make_float4(0.f, 0.f, 0.f, 0.f);
        }
        __syncthreads();
        int r0 = tid >> 5, j = tid & 31;
        float acc0 = 0.f, acc1 = 0.f, acc2 = 0.f, acc3 = 0.f;
        float acc4 = 0.f, acc5 = 0.f, acc6 = 0.f, acc7 = 0.f;
        #pragma unroll 2
        for (int k4 = 0; k4 < 32; ++k4) {
            float4 wv = *(const float4*)&lwT[j][k4 * 4];
            float4 x0 = *(const float4*)&lx[r0     ][k4 * 4];
            float4 x1 = *(const float4*)&lx[r0 +  8][k4 * 4];
            float4 x2 = *(const float4*)&lx[r0 + 16][k4 * 4];
            float4 x3 = *(const float4*)&lx[r0 + 24][k4 * 4];
            acc0 += x0.x * wv.x + x0.y * wv.y + x0.z * wv.z + x0.w * wv.w;
            acc1 += x1.x * wv.x + x1.y * wv.y + x1.z * wv.z + x1.w * wv.w;
            acc2 += x2.x * wv.x + x2.y * wv.y + x2.z * wv.z + x2.w * wv.w;
            acc3 += x3.x * wv.x + x3.y * wv.y + x3.z * wv.z + x3.w * wv.w;
            float4 x4v = *(const float4*)&lx[r0 + 32][k4 * 4];
            float4 x5  = *(const float4*)&lx[r0 + 40][k4 * 4];
            float4 x6  = *(const float4*)&lx[r0 + 48][k4 * 4];
            float4 x7  = *(const float4*)&lx[r0 + 56][k4 * 4];
            acc4 += x4v.x * wv.x + x4v.y * wv.y + x4v.z * wv.z + x4v.w * wv.w;
            acc5 += x5.x * wv.x + x5.y * wv.y + x5.z * wv.z + x5.w * wv.w;
            acc6 += x6.x * wv.x + x6.y * wv.y + x6.z * wv.z + x6.w * wv.w;
            acc7 += x7.x * wv.x + x7.y * wv.y + x7.z * wv.z + x7.w * wv.w;
        }
        float accs[8] = {acc0, acc1, acc2, acc3, acc4, acc5, acc6, acc7};
        #pragma unroll
        for (int q = 0; q < 8; ++q) {
            int node = node0 + r0 + q * 8;
            if (node < n) {
                if (j < HID) xs[(size_t)node * HID + j] = accs[q];
                else         xn[(size_t)node * HID + (j - 16)] = accs[q];
            }
        }
    }
}

// load per-bucket run table + prefix; returns cnt. 512 threads.
__device__ __forceinline__ int load_runs(const int* __restrict__ loffT, int b,
                                         int B, int* runstart, int* runoff,
                                         int* sm) {
    int tid = threadIdx.x;
    if (tid < 256) {
        int len = 0, st = 0;
        if (tid < B) {
            int lo = loffT[(size_t)b * B + tid];
            int hi = loffT[(size_t)(b + 1) * B + tid];
            st = tid * EPB + lo;
            len = hi - lo;
        }
        runstart[tid] = st;
        sm[tid] = len;
    }
    __syncthreads();
    for (int off = 1; off < 256; off <<= 1) {
        int u = (tid < 256 && tid >= off) ? sm[tid - off] : 0;
        __syncthreads();
        if (tid < 256) sm[tid] += u;
        __syncthreads();
    }
    if (tid < 256) runoff[tid + 1] = sm[tid];
    if (tid == 0) runoff[0] = 0;
    __syncthreads();
    return runoff[256];
}

__device__ __forceinline__ int find_run(const int* runoff, int i) {
    int lo = 0, hi = 256;
    #pragma unroll
    for (int it = 0; it < 8; ++it) {
        int mid = (lo + hi) >> 1;
        if (runoff[mid] <= i) lo = mid; else hi = mid;
    }
    return lo;
}

// ---- K2: per-bucket: stage via run binary-search -> rank -> float4 pull of xn
//      -> h = relu(xs + mean + b1). Emits ranked fsrc[b*CAP+..] + lofsG.
__global__ void __launch_bounds__(512)
k_agg1(const unsigned* __restrict__ bedge, const int* __restrict__ loffT,
       const float* __restrict__ xs, const float* __restrict__ xn,
       const float* __restrict__ b1, float* __restrict__ h,
       int* __restrict__ fsrc, int* __restrict__ lofsG, int n, int B) {
    __shared__ int runstart[256];
    __shared__ int runoff[257];
    __shared__ int sm[256];
    __shared__ int ltmp[CAP];
    __shared__ int lsrc[CAP];
    __shared__ int lcnt[BK];
    __shared__ int lofs[BK + 1];
    __shared__ int lcur[BK];
    __shared__ float facc[BK][HID];
    int tid = threadIdx.x, b = blockIdx.x;
    int cnt = load_runs(loffT, b, B, runstart, runoff, sm);
    bool fits = (cnt <= CAP);
    if (tid < BK) lcnt[tid] = 0;
    __syncthreads();
    int node0 = b * BK;
    if (fits) {
        for (int i = tid; i < cnt; i += 512) {
            int rb = find_run(runoff, i);
            int p = (int)bedge[runstart[rb] + (i - runoff[rb])];
            ltmp[i] = p;
            atomicAdd(&lcnt[p & 63], 1);
        }
        __syncthreads();
        if (tid < BK) {
            int v = lcnt[tid];
            #pragma unroll
            for (int off = 1; off < 64; off <<= 1) {
                int t = __shfl_up(v, off);
                if (tid >= off) v += t;
            }
            lofs[tid + 1] = v;
            if (tid == 0) lofs[0] = 0;
            lcur[tid] = lofs[tid];
        }
        __syncthreads();
        for (int i = tid; i < cnt; i += 512) {
            int p = ltmp[i];
            int r = atomicAdd(&lcur[p & 63], 1);
            lsrc[r] = p >> 6;
        }
        __syncthreads();
        if (tid <= BK) lofsG[(size_t)b * (BK + 1) + tid] = lofs[tid];
        for (int i = tid; i < cnt; i += 512) fsrc[(size_t)b * CAP + i] = lsrc[i];
        int d4 = tid & 3;
        int half = (tid >> 2) & 1;
        int nl = tid >> 3;
        int node = node0 + nl;
        int t0 = lofs[nl], t1 = lofs[nl + 1];
        const float4* xn4 = (const float4*)xn;
        float4 a0 = make_float4(0.f, 0.f, 0.f, 0.f);
        float4 a1 = make_float4(0.f, 0.f, 0.f, 0.f);
        int k = t0 + half;
        for (; k + 2 < t1; k += 4) {
            f4add(a0, xn4[(size_t)lsrc[k] * 4 + d4]);
            f4add(a1, xn4[(size_t)lsrc[k + 2] * 4 + d4]);
        }
        if (k < t1) f4add(a0, xn4[(size_t)lsrc[k] * 4 + d4]);
        f4add(a0, a1);
        a0.x += __shfl_xor(a0.x, 4);
        a0.y += __shfl_xor(a0.y, 4);
        a0.z += __shfl_xor(a0.z, 4);
        a0.w += __shfl_xor(a0.w, 4);
        if (half == 0 && node < n) {
            float inv = 1.0f / fmaxf((float)(t1 - t0), 1.0f);
            float4 xv = ((const float4*)xs)[(size_t)node * 4 + d4];
            float4 bv = ((const float4*)b1)[d4];
            float4 hv;
            hv.x = fmaxf(xv.x + a0.x * inv + bv.x, 0.f);
            hv.y = fmaxf(xv.y + a0.y * inv + bv.y, 0.f);
            hv.z = fmaxf(xv.z + a0.z * inv + bv.z, 0.f);
            hv.w = fmaxf(xv.w + a0.w * inv + bv.w, 0.f);
            ((float4*)h)[(size_t)node * 4 + d4] = hv;
        }
    } else {
        for (int i = tid; i < BK * HID; i += 512) ((float*)facc)[i] = 0.f;
        __syncthreads();
        for (long long idx = tid; idx < (long long)cnt * HID; idx += 512) {
            int i = (int)(idx >> 4), d = (int)(idx & 15);
            int rb = find_run(runoff, i);
            int p = (int)bedge[runstart[rb] + (i - runoff[rb])];
            atomicAdd(&facc[p & 63][d], xn[(size_t)(p >> 6) * HID + d]);
            if (d == 0) atomicAdd(&lcnt[p & 63], 1);
        }
        __syncthreads();
        if (tid < BK) {
            int v = lcnt[tid];
            #pragma unroll
            for (int off = 1; off < 64; off <<= 1) {
                int t = __shfl_up(v, off);
                if (tid >= off) v += t;
            }
            lofs[tid + 1] = v;
            if (tid == 0) lofs[0] = 0;
        }
        __syncthreads();
        if (tid <= BK) lofsG[(size_t)b * (BK + 1) + tid] = lofs[tid];
        for (int i = tid; i < BK * HID; i += 512) {
            int nl = i >> 4, d = i & 15;
            int node = node0 + nl;
            if (node < n) {
                float dg = fmaxf((float)lcnt[nl], 1.0f);
                float v = xs[(size_t)node * HID + d] + facc[nl][d] / dg + b1[d];
                h[(size_t)node * HID + d] = fmaxf(v, 0.f);
            }
        }
    }
}

// ---- K3: per-bucket float4 pull of h (ranked fsrc) + float4 output GEMM.
__global__ void __launch_bounds__(512)
k_agg2_out(const unsigned* __restrict__ bedge, const int* __restrict__ loffT,
           const int* __restrict__ fsrc, const int* __restrict__ lofsG,
           const float* __restrict__ h,
           const float* __restrict__ Ws2, const float* __restrict__ Wn2,
           const float* __restrict__ b2, float* __restrict__ out, int n, int B) {
    __shared__ int   runstart[256];
    __shared__ int   runoff[257];
    __shared__ int   smi[256];
    __shared__ int   lidx[CAP];
    __shared__ int   lofs[BK + 1];
    __shared__ float lh[BK][HID];
    __shared__ float lagg[BK][HID];
    __shared__ float lws[HID][OUT];
    __shared__ float lwn[HID][OUT];
    __shared__ float lb2v[OUT];
    int tid = threadIdx.x, b = blockIdx.x;
    int node0 = b * BK;
    if (tid <= BK) lofs[tid] = lofsG[(size_t)b * (BK + 1) + tid];
    for (int i = tid; i < BK * HID; i += 512) {
        int node = node0 + (i >> 4);
        lh[i >> 4][i & 15] = (node < n) ? h[(size_t)node * HID + (i & 15)] : 0.f;
    }
    for (int i = tid; i < HID * OUT; i += 512) {
        ((float*)lws)[i] = Ws2[i];
        ((float*)lwn)[i] = Wn2[i];
    }
    if (tid < OUT) lb2v[tid] = b2[tid];
    __syncthreads();
    int cnt = lofs[BK];
    bool fits = (cnt <= CAP);
    if (fits) {
        for (int i = tid; i < cnt; i += 512) lidx[i] = fsrc[(size_t)b * CAP + i];
        __syncthreads();
        int d4 = tid & 3;
        int half = (tid >> 2) & 1;
        int nl = tid >> 3;
        int t0 = lofs[nl], t1 = lofs[nl + 1];
        const float4* h4 = (const float4*)h;
        float4 a0 = make_float4(0.f, 0.f, 0.f, 0.f);
        float4 a1 = make_float4(0.f, 0.f, 0.f, 0.f);
        int k = t0 + half;
        for (; k + 2 < t1; k += 4) {
            f4add(a0, h4[(size_t)lidx[k] * 4 + d4]);
            f4add(a1, h4[(size_t)lidx[k + 2] * 4 + d4]);
        }
        if (k < t1) f4add(a0, h4[(size_t)lidx[k] * 4 + d4]);
        f4add(a0, a1);
        a0.x += __shfl_xor(a0.x, 4);
        a0.y += __shfl_xor(a0.y, 4);
        a0.z += __shfl_xor(a0.z, 4);
        a0.w += __shfl_xor(a0.w, 4);
        if (half == 0) {
            float inv = 1.0f / fmaxf((float)(t1 - t0), 1.0f);
            float4 r;
            r.x = a0.x * inv; r.y = a0.y * inv; r.z = a0.z * inv; r.w = a0.w * inv;
            *(float4*)&lagg[nl][d4 * 4] = r;
        }
    } else {
        int cnt2 = load_runs(loffT, b, B, runstart, runoff, smi);
        for (int i = tid; i < BK * HID; i += 512) ((float*)lagg)[i] = 0.f;
        __syncthreads();
        for (long long idx = tid; idx < (long long)cnt2 * HID; idx += 512) {
            int i = (int)(idx >> 4), d = (int)(idx & 15);
            int rb = find_run(runoff, i);
            int p = (int)bedge[runstart[rb] + (i - runoff[rb])];
            atomicAdd(&lagg[p & 63][d], h[(size_t)(p >> 6) * HID + d]);
        }
        __syncthreads();
        for (int i = tid; i < BK * HID; i += 512) {
            int nl = i >> 4, d = i & 15;
            float dg = fmaxf((float)(lofs[nl + 1] - lofs[nl]), 1.0f);
            lagg[nl][d] /= dg;
        }
    }
    __syncthreads();
    // float4 output GEMM: thread = (nl, o4); lws/lwn read as b128, out as float4
    for (int i = tid; i < BK * (OUT / 4); i += 512) {
        int nl2 = i >> 4, o4 = i & 15;
        int node = node0 + nl2;
        if (node >= n) continue;
        float4 acm = *(const float4*)&lb2v[o4 * 4];
        #pragma unroll
        for (int j = 0; j < HID; ++j) {
            float hj = lh[nl2][j];
            float aj = lagg[nl2][j];
            float4 ws4 = *(const float4*)&lws[j][o4 * 4];
            float4 wn4 = *(const float4*)&lwn[j][o4 * 4];
            acm.x += hj * ws4.x + aj * wn4.x;
            acm.y += hj * ws4.y + aj * wn4.y;
            acm.z += hj * ws4.z + aj * wn4.z;
            acm.w += hj * ws4.w + aj * wn4.w;
        }
        *(float4*)&out[(size_t)node * OUT + o4 * 4] = acm;
    }
}

extern "C" void kernel_launch(void* const* d_in, const int* in_sizes, int n_in,
                              void* d_out, int out_size, void* d_ws, size_t ws_size,
                              hipStream_t stream) {
    const float* x   = (const float*)d_in[0];
    const int*   src = (const int*)d_in[1];
    const int*   dst = (const int*)d_in[2];
    const float* Ws1 = (const float*)d_in[3];
    const float* Wn1 = (const float*)d_in[4];
    const float* b1  = (const float*)d_in[5];
    const float* Ws2 = (const float*)d_in[6];
    const float* Wn2 = (const float*)d_in[7];
    const float* b2  = (const float*)d_in[8];
    float* out = (float*)d_out;

    int n = in_sizes[0] / IN;          // 50000
    int e = in_sizes[1];               // 800000
    int K = (n + BK - 1) / BK;         // 782 buckets
    int B = (e + EPB - 1) / EPB;       // 196 partition blocks (<=256)
    int nproj = (n + PBN - 1) / PBN;   // 782 proj blocks

    // ws: loffT[(K+1)*B] | bedge[B*EPB] | fsrc[K*CAP] | lofsG[K*(BK+1)] | xs | xn | h
    int* loffT = (int*)d_ws;
    unsigned* bedge = (unsigned*)(loffT + (size_t)(K + 1) * B);
    int* fsrc  = (int*)(bedge + (size_t)B * EPB);
    int* lofsG = fsrc + (size_t)K * CAP;
    float* xs = (float*)(lofsG + (size_t)K * (BK + 1));
    float* xn = xs + (size_t)n * HID;
    float* h  = xn + (size_t)n * HID;

    k_proj_part<<<B + nproj, 256, 0, stream>>>(x, Ws1, Wn1, src, dst, xs, xn,
                                               loffT, bedge, n, e, K, B);
    k_agg1<<<K, 512, 0, stream>>>(bedge, loffT, xs, xn, b1, h, fsrc, lofsG, n, B);
    k_agg2_out<<<K, 512, 0, stream>>>(bedge, loffT, fsrc, lofsG, h,
                                      Ws2, Wn2, b2, out, n, B);
}

// Round 20
// 58.557 us; speedup vs baseline: 1.0320x; 1.0320x over previous
//
#include <hip/hip_runtime.h>

#define IN   128
#define HID  16
#define OUT  64
#define BK   64        // nodes per bucket (bucket = dst >> 6)
#define EPB  4096      // edges per partition block (B=196 blocks)
#define CAP  2048      // staging capacity per bucket (mean ~1024, 30-sigma safe)
#define PBN  32        // nodes per proj block (4 per thread) — R18-proven optimum

__device__ __forceinline__ void f4add(float4& a, const float4 v) {
    a.x += v.x; a.y += v.y; a.z += v.z; a.w += v.w;
}

// ---- K1 (fused): blocks [0,B) = block-local partition (first => overlapped).
//      Blocks [B, B+nproj) = proj, 32 nodes/block, 4 nodes/thread: each
//      weight-row LDS read reused 4x (x-row reads are half-wave broadcast).
__global__ void __launch_bounds__(256)
k_proj_part(const float* __restrict__ x,
            const float* __restrict__ Ws,
            const float* __restrict__ Wn,
            const int* __restrict__ src,
            const int* __restrict__ dst,
            float* __restrict__ xs,
            float* __restrict__ xn,
            int* __restrict__ loffT,
            unsigned* __restrict__ bedge,
            int n, int e, int K, int B) {
    __shared__ __align__(16) float smem[4224 + 4096];  // lwT[32][132] + lx[32][128]
    int tid = threadIdx.x;   // 256
    if ((int)blockIdx.x < B) {
        // ---- partition block (R16/R17-proven body) ----
        int* ism = (int*)smem;
        int* lh  = ism;            // [1024] counts, later cursors
        int* lsc = ism + 1024;     // [K+1]
        int* sm  = ism + 2050;     // [256]
        int blk = blockIdx.x;
        for (int i = tid; i < K; i += 256) lh[i] = 0;
        __syncthreads();
        const int4* d4 = (const int4*)dst;
        #pragma unroll
        for (int it = 0; it < EPB / 1024; ++it) {
            int i4 = blk * (EPB / 4) + it * 256 + tid;
            int elem = i4 * 4;
            if (elem + 3 < e) {
                int4 v = d4[i4];
                atomicAdd(&lh[v.x >> 6], 1);
                atomicAdd(&lh[v.y >> 6], 1);
                atomicAdd(&lh[v.z >> 6], 1);
                atomicAdd(&lh[v.w >> 6], 1);
            } else {
                for (int jj = elem; jj < e && jj < elem + 4; ++jj)
                    atomicAdd(&lh[dst[jj] >> 6], 1);
            }
        }
        __syncthreads();
        int C = (K + 255) >> 8;
        int i0 = tid * C, i1 = min(i0 + C, K);
        int s = 0;
        for (int i = i0; i < i1; ++i) s += lh[i];
        sm[tid] = s;
        __syncthreads();
        for (int off = 1; off < 256; off <<= 1) {
            int u = (tid >= off) ? sm[tid - off] : 0;
            __syncthreads();
            sm[tid] += u;
            __syncthreads();
        }
        int run = sm[tid] - s;
        for (int i = i0; i < i1; ++i) {
            int vv = lh[i];
            lsc[i] = run;
            run += vv;
        }
        if (tid == 255) lsc[K] = sm[255];
        __syncthreads();
        for (int bb = tid; bb <= K; bb += 256)
            loffT[(size_t)bb * B + blk] = lsc[bb];
        for (int bb = tid; bb < K; bb += 256) lh[bb] = lsc[bb];  // cursors
        __syncthreads();
        unsigned base = (unsigned)blk * EPB;
        const int4* s4 = (const int4*)src;
        #pragma unroll
        for (int it = 0; it < EPB / 1024; ++it) {
            int i4 = blk * (EPB / 4) + it * 256 + tid;
            int elem = i4 * 4;
            if (elem + 3 < e) {
                int4 sv = s4[i4];
                int4 dv = d4[i4];
                int p0 = atomicAdd(&lh[dv.x >> 6], 1);
                int p1 = atomicAdd(&lh[dv.y >> 6], 1);
                int p2 = atomicAdd(&lh[dv.z >> 6], 1);
                int p3 = atomicAdd(&lh[dv.w >> 6], 1);
                bedge[base + p0] = ((unsigned)sv.x << 6) | (unsigned)(dv.x & 63);
                bedge[base + p1] = ((unsigned)sv.y << 6) | (unsigned)(dv.y & 63);
                bedge[base + p2] = ((unsigned)sv.z << 6) | (unsigned)(dv.z & 63);
                bedge[base + p3] = ((unsigned)sv.w << 6) | (unsigned)(dv.w & 63);
            } else {
                for (int jj = elem; jj < e && jj < elem + 4; ++jj) {
                    int pos = atomicAdd(&lh[dst[jj] >> 6], 1);
                    bedge[base + pos] = ((unsigned)src[jj] << 6) | (unsigned)(dst[jj] & 63);
                }
            }
        }
    } else {
        // ---- proj block: 32 nodes, 4 per thread (rows r0, r0+8, r0+16, r0+24) ----
        float (*lwT)[132] = (float (*)[132])smem;          // [32][132]
        float (*lx)[IN]   = (float (*)[IN])(smem + 4224);  // [32][128]
        for (int i = tid; i < IN * 32; i += 256) {
            int k = i >> 5, j = i & 31;
            lwT[j][k] = (j < HID) ? Ws[k * HID + j] : Wn[k * HID + (j - 16)];
        }
        int node0 = (blockIdx.x - B) * PBN;
        const float4* x4 = (const float4*)x;
        float4* lx4 = (float4*)lx;     // [32][32] float4 = 1024
        #pragma unroll
        for (int q = 0; q < 4; ++q) {
            int i = q * 256 + tid;
            int r = i >> 5, c4 = i & 31;
            int node = node0 + r;
            lx4[i] = (node < n) ? x4[(size_t)node * 32 + c4]
                                : make_float4(0.f, 0.f, 0.f, 0.f);
        }
        __syncthreads();
        int r0 = tid >> 5, j = tid & 31;
        const float4* lxr0 = (const float4*)lx[r0];
        const float4* lxr1 = (const float4*)lx[r0 + 8];
        const float4* lxr2 = (const float4*)lx[r0 + 16];
        const float4* lxr3 = (const float4*)lx[r0 + 24];
        float acc0 = 0.f, acc1 = 0.f, acc2 = 0.f, acc3 = 0.f;
        #pragma unroll 4
        for (int k4 = 0; k4 < 32; ++k4) {
            float4 wv = *(const float4*)&lwT[j][k4 * 4];
            float4 x0 = lxr0[k4];
            float4 x1 = lxr1[k4];
            float4 x2 = lxr2[k4];
            float4 x3 = lxr3[k4];
            acc0 += x0.x * wv.x + x0.y * wv.y + x0.z * wv.z + x0.w * wv.w;
            acc1 += x1.x * wv.x + x1.y * wv.y + x1.z * wv.z + x1.w * wv.w;
            acc2 += x2.x * wv.x + x2.y * wv.y + x2.z * wv.z + x2.w * wv.w;
            acc3 += x3.x * wv.x + x3.y * wv.y + x3.z * wv.z + x3.w * wv.w;
        }
        float accs[4] = {acc0, acc1, acc2, acc3};
        #pragma unroll
        for (int q = 0; q < 4; ++q) {
            int node = node0 + r0 + q * 8;
            if (node < n) {
                if (j < HID) xs[(size_t)node * HID + j] = accs[q];
                else         xn[(size_t)node * HID + (j - 16)] = accs[q];
            }
        }
    }
}

// load per-bucket run table + prefix; returns cnt. 512 threads.
__device__ __forceinline__ int load_runs(const int* __restrict__ loffT, int b,
                                         int B, int* runstart, int* runoff,
                                         int* sm) {
    int tid = threadIdx.x;
    if (tid < 256) {
        int len = 0, st = 0;
        if (tid < B) {
            int lo = loffT[(size_t)b * B + tid];
            int hi = loffT[(size_t)(b + 1) * B + tid];
            st = tid * EPB + lo;
            len = hi - lo;
        }
        runstart[tid] = st;
        sm[tid] = len;
    }
    __syncthreads();
    for (int off = 1; off < 256; off <<= 1) {
        int u = (tid < 256 && tid >= off) ? sm[tid - off] : 0;
        __syncthreads();
        if (tid < 256) sm[tid] += u;
        __syncthreads();
    }
    if (tid < 256) runoff[tid + 1] = sm[tid];
    if (tid == 0) runoff[0] = 0;
    __syncthreads();
    return runoff[256];
}

__device__ __forceinline__ int find_run(const int* runoff, int i) {
    int lo = 0, hi = 256;
    #pragma unroll
    for (int it = 0; it < 8; ++it) {
        int mid = (lo + hi) >> 1;
        if (runoff[mid] <= i) lo = mid; else hi = mid;
    }
    return lo;
}

// ---- K2: per-bucket: stage via run binary-search -> rank -> float4 pull of xn
//      -> h = relu(xs + mean + b1). Emits ranked fsrc[b*CAP+..] + lofsG.
__global__ void __launch_bounds__(512)
k_agg1(const unsigned* __restrict__ bedge, const int* __restrict__ loffT,
       const float* __restrict__ xs, const float* __restrict__ xn,
       const float* __restrict__ b1, float* __restrict__ h,
       int* __restrict__ fsrc, int* __restrict__ lofsG, int n, int B) {
    __shared__ int runstart[256];
    __shared__ int runoff[257];
    __shared__ int sm[256];
    __shared__ int ltmp[CAP];
    __shared__ int lsrc[CAP];
    __shared__ int lcnt[BK];
    __shared__ int lofs[BK + 1];
    __shared__ int lcur[BK];
    __shared__ float facc[BK][HID];
    int tid = threadIdx.x, b = blockIdx.x;
    int cnt = load_runs(loffT, b, B, runstart, runoff, sm);
    bool fits = (cnt <= CAP);
    if (tid < BK) lcnt[tid] = 0;
    __syncthreads();
    int node0 = b * BK;
    if (fits) {
        for (int i = tid; i < cnt; i += 512) {
            int rb = find_run(runoff, i);
            int p = (int)bedge[runstart[rb] + (i - runoff[rb])];
            ltmp[i] = p;
            atomicAdd(&lcnt[p & 63], 1);
        }
        __syncthreads();
        if (tid < BK) {
            int v = lcnt[tid];
            #pragma unroll
            for (int off = 1; off < 64; off <<= 1) {
                int t = __shfl_up(v, off);
                if (tid >= off) v += t;
            }
            lofs[tid + 1] = v;
            if (tid == 0) lofs[0] = 0;
            lcur[tid] = lofs[tid];
        }
        __syncthreads();
        for (int i = tid; i < cnt; i += 512) {
            int p = ltmp[i];
            int r = atomicAdd(&lcur[p & 63], 1);
            lsrc[r] = p >> 6;
        }
        __syncthreads();
        if (tid <= BK) lofsG[(size_t)b * (BK + 1) + tid] = lofs[tid];
        for (int i = tid; i < cnt; i += 512) fsrc[(size_t)b * CAP + i] = lsrc[i];
        int d4 = tid & 3;
        int half = (tid >> 2) & 1;
        int nl = tid >> 3;
        int node = node0 + nl;
        int t0 = lofs[nl], t1 = lofs[nl + 1];
        const float4* xn4 = (const float4*)xn;
        float4 a0 = make_float4(0.f, 0.f, 0.f, 0.f);
        float4 a1 = make_float4(0.f, 0.f, 0.f, 0.f);
        int k = t0 + half;
        for (; k + 2 < t1; k += 4) {
            f4add(a0, xn4[(size_t)lsrc[k] * 4 + d4]);
            f4add(a1, xn4[(size_t)lsrc[k + 2] * 4 + d4]);
        }
        if (k < t1) f4add(a0, xn4[(size_t)lsrc[k] * 4 + d4]);
        f4add(a0, a1);
        a0.x += __shfl_xor(a0.x, 4);
        a0.y += __shfl_xor(a0.y, 4);
        a0.z += __shfl_xor(a0.z, 4);
        a0.w += __shfl_xor(a0.w, 4);
        if (half == 0 && node < n) {
            float inv = 1.0f / fmaxf((float)(t1 - t0), 1.0f);
            float4 xv = ((const float4*)xs)[(size_t)node * 4 + d4];
            float4 bv = ((const float4*)b1)[d4];
            float4 hv;
            hv.x = fmaxf(xv.x + a0.x * inv + bv.x, 0.f);
            hv.y = fmaxf(xv.y + a0.y * inv + bv.y, 0.f);
            hv.z = fmaxf(xv.z + a0.z * inv + bv.z, 0.f);
            hv.w = fmaxf(xv.w + a0.w * inv + bv.w, 0.f);
            ((float4*)h)[(size_t)node * 4 + d4] = hv;
        }
    } else {
        for (int i = tid; i < BK * HID; i += 512) ((float*)facc)[i] = 0.f;
        __syncthreads();
        for (long long idx = tid; idx < (long long)cnt * HID; idx += 512) {
            int i = (int)(idx >> 4), d = (int)(idx & 15);
            int rb = find_run(runoff, i);
            int p = (int)bedge[runstart[rb] + (i - runoff[rb])];
            atomicAdd(&facc[p & 63][d], xn[(size_t)(p >> 6) * HID + d]);
            if (d == 0) atomicAdd(&lcnt[p & 63], 1);
        }
        __syncthreads();
        if (tid < BK) {
            int v = lcnt[tid];
            #pragma unroll
            for (int off = 1; off < 64; off <<= 1) {
                int t = __shfl_up(v, off);
                if (tid >= off) v += t;
            }
            lofs[tid + 1] = v;
            if (tid == 0) lofs[0] = 0;
        }
        __syncthreads();
        if (tid <= BK) lofsG[(size_t)b * (BK + 1) + tid] = lofs[tid];
        for (int i = tid; i < BK * HID; i += 512) {
            int nl = i >> 4, d = i & 15;
            int node = node0 + nl;
            if (node < n) {
                float dg = fmaxf((float)lcnt[nl], 1.0f);
                float v = xs[(size_t)node * HID + d] + facc[nl][d] / dg + b1[d];
                h[(size_t)node * HID + d] = fmaxf(v, 0.f);
            }
        }
    }
}

// ---- K3: per-bucket float4 pull of h (ranked fsrc) + float4 output GEMM.
__global__ void __launch_bounds__(512)
k_agg2_out(const unsigned* __restrict__ bedge, const int* __restrict__ loffT,
           const int* __restrict__ fsrc, const int* __restrict__ lofsG,
           const float* __restrict__ h,
           const float* __restrict__ Ws2, const float* __restrict__ Wn2,
           const float* __restrict__ b2, float* __restrict__ out, int n, int B) {
    __shared__ int   runstart[256];
    __shared__ int   runoff[257];
    __shared__ int   smi[256];
    __shared__ int   lidx[CAP];
    __shared__ int   lofs[BK + 1];
    __shared__ float lh[BK][HID];
    __shared__ float lagg[BK][HID];
    __shared__ float lws[HID][OUT];
    __shared__ float lwn[HID][OUT];
    __shared__ float lb2v[OUT];
    int tid = threadIdx.x, b = blockIdx.x;
    int node0 = b * BK;
    if (tid <= BK) lofs[tid] = lofsG[(size_t)b * (BK + 1) + tid];
    for (int i = tid; i < BK * HID; i += 512) {
        int node = node0 + (i >> 4);
        lh[i >> 4][i & 15] = (node < n) ? h[(size_t)node * HID + (i & 15)] : 0.f;
    }
    for (int i = tid; i < HID * OUT; i += 512) {
        ((float*)lws)[i] = Ws2[i];
        ((float*)lwn)[i] = Wn2[i];
    }
    if (tid < OUT) lb2v[tid] = b2[tid];
    __syncthreads();
    int cnt = lofs[BK];
    bool fits = (cnt <= CAP);
    if (fits) {
        for (int i = tid; i < cnt; i += 512) lidx[i] = fsrc[(size_t)b * CAP + i];
        __syncthreads();
        int d4 = tid & 3;
        int half = (tid >> 2) & 1;
        int nl = tid >> 3;
        int t0 = lofs[nl], t1 = lofs[nl + 1];
        const float4* h4 = (const float4*)h;
        float4 a0 = make_float4(0.f, 0.f, 0.f, 0.f);
        float4 a1 = make_float4(0.f, 0.f, 0.f, 0.f);
        int k = t0 + half;
        for (; k + 2 < t1; k += 4) {
            f4add(a0, h4[(size_t)lidx[k] * 4 + d4]);
            f4add(a1, h4[(size_t)lidx[k + 2] * 4 + d4]);
        }
        if (k < t1) f4add(a0, h4[(size_t)lidx[k] * 4 + d4]);
        f4add(a0, a1);
        a0.x += __shfl_xor(a0.x, 4);
        a0.y += __shfl_xor(a0.y, 4);
        a0.z += __shfl_xor(a0.z, 4);
        a0.w += __shfl_xor(a0.w, 4);
        if (half == 0) {
            float inv = 1.0f / fmaxf((float)(t1 - t0), 1.0f);
            float4 r;
            r.x = a0.x * inv; r.y = a0.y * inv; r.z = a0.z * inv; r.w = a0.w * inv;
            *(float4*)&lagg[nl][d4 * 4] = r;
        }
    } else {
        int cnt2 = load_runs(loffT, b, B, runstart, runoff, smi);
        for (int i = tid; i < BK * HID; i += 512) ((float*)lagg)[i] = 0.f;
        __syncthreads();
        for (long long idx = tid; idx < (long long)cnt2 * HID; idx += 512) {
            int i = (int)(idx >> 4), d = (int)(idx & 15);
            int rb = find_run(runoff, i);
            int p = (int)bedge[runstart[rb] + (i - runoff[rb])];
            atomicAdd(&lagg[p & 63][d], h[(size_t)(p >> 6) * HID + d]);
        }
        __syncthreads();
        for (int i = tid; i < BK * HID; i += 512) {
            int nl = i >> 4, d = i & 15;
            float dg = fmaxf((float)(lofs[nl + 1] - lofs[nl]), 1.0f);
            lagg[nl][d] /= dg;
        }
    }
    __syncthreads();
    // float4 output GEMM: thread = (nl, o4); lws/lwn read as b128, out as float4
    for (int i = tid; i < BK * (OUT / 4); i += 512) {
        int nl2 = i >> 4, o4 = i & 15;
        int node = node0 + nl2;
        if (node >= n) continue;
        float4 acm = *(const float4*)&lb2v[o4 * 4];
        #pragma unroll
        for (int j = 0; j < HID; ++j) {
            float hj = lh[nl2][j];
            float aj = lagg[nl2][j];
            float4 ws4 = *(const float4*)&lws[j][o4 * 4];
            float4 wn4 = *(const float4*)&lwn[j][o4 * 4];
            acm.x += hj * ws4.x + aj * wn4.x;
            acm.y += hj * ws4.y + aj * wn4.y;
            acm.z += hj * ws4.z + aj * wn4.z;
            acm.w += hj * ws4.w + aj * wn4.w;
        }
        *(float4*)&out[(size_t)node * OUT + o4 * 4] = acm;
    }
}

extern "C" void kernel_launch(void* const* d_in, const int* in_sizes, int n_in,
                              void* d_out, int out_size, void* d_ws, size_t ws_size,
                              hipStream_t stream) {
    const float* x   = (const float*)d_in[0];
    const int*   src = (const int*)d_in[1];
    const int*   dst = (const int*)d_in[2];
    const float* Ws1 = (const float*)d_in[3];
    const float* Wn1 = (const float*)d_in[4];
    const float* b1  = (const float*)d_in[5];
    const float* Ws2 = (const float*)d_in[6];
    const float* Wn2 = (const float*)d_in[7];
    const float* b2  = (const float*)d_in[8];
    float* out = (float*)d_out;

    int n = in_sizes[0] / IN;          // 50000
    int e = in_sizes[1];               // 800000
    int K = (n + BK - 1) / BK;         // 782 buckets
    int B = (e + EPB - 1) / EPB;       // 196 partition blocks (<=256)
    int nproj = (n + PBN - 1) / PBN;   // 1563 proj blocks

    // ws: loffT[(K+1)*B] | bedge[B*EPB] | fsrc[K*CAP] | lofsG[K*(BK+1)] | xs | xn | h
    int* loffT = (int*)d_ws;
    unsigned* bedge = (unsigned*)(loffT + (size_t)(K + 1) * B);
    int* fsrc  = (int*)(bedge + (size_t)B * EPB);
    int* lofsG = fsrc + (size_t)K * CAP;
    float* xs = (float*)(lofsG + (size_t)K * (BK + 1));
    float* xn = xs + (size_t)n * HID;
    float* h  = xn + (size_t)n * HID;

    k_proj_part<<<B + nproj, 256, 0, stream>>>(x, Ws1, Wn1, src, dst, xs, xn,
                                               loffT, bedge, n, e, K, B);
    k_agg1<<<K, 512, 0, stream>>>(bedge, loffT, xs, xn, b1, h, fsrc, lofsG, n, B);
    k_agg2_out<<<K, 512, 0, stream>>>(bedge, loffT, fsrc, lofsG, h,
                                      Ws2, Wn2, b2, out, n, B);
}